// Round 1
// baseline (1121.244 us; speedup 1.0000x reference)
//
#include <hip/hip_runtime.h>
#include <hip/hip_bf16.h>
#include <math.h>

// Problem constants (from reference): B=2, N=4096, E=16384, D=64, OUT=64
#define BB 2
#define NN 4096      // 2^12
#define EE 16384     // 2^14
#define DD 64
#define OO 64
// flat element index in [B,N,E]: fe = b*(N*E) + n*E + e ; N*E = 2^26, E = 2^14

// ---------------------------------------------------------------------------
// Kernel 1: recover ri_idx/ro_idx from the one-hot incidence matrices.
// Each [b, :, e] column of Ri has exactly one nonzero (value 1.0) at row n.
// Stream both 512MB matrices with float4 loads; the rare nonzero lane writes
// its row index. Exactly one writer per (b,e) -> plain store, no atomics.
// This kernel is the HBM floor of the whole problem (~1.07 GB read).
// ---------------------------------------------------------------------------
__global__ __launch_bounds__(256) void extract_idx_kernel(
    const float* __restrict__ Ri, const float* __restrict__ Ro,
    int* __restrict__ ri_idx, int* __restrict__ ro_idx)
{
    const unsigned total4 = (unsigned)(BB) * (unsigned)(NN) * (unsigned)(EE / 4); // 33,554,432
    unsigned stride = gridDim.x * blockDim.x;
    for (unsigned i = blockIdx.x * blockDim.x + threadIdx.x; i < total4; i += stride) {
        float4 vi = ((const float4*)Ri)[i];
        float4 vo = ((const float4*)Ro)[i];
        unsigned fe = i * 4u;                 // flat element index (fits in 27 bits)
        int e = (int)(fe & (EE - 1));
        int n = (int)((fe >> 14) & (NN - 1));
        int b = (int)(fe >> 26);
        int base = b * EE + e;
        if (vi.x != 0.f) ri_idx[base + 0] = n;
        if (vi.y != 0.f) ri_idx[base + 1] = n;
        if (vi.z != 0.f) ri_idx[base + 2] = n;
        if (vi.w != 0.f) ri_idx[base + 3] = n;
        if (vo.x != 0.f) ro_idx[base + 0] = n;
        if (vo.y != 0.f) ro_idx[base + 1] = n;
        if (vo.z != 0.f) ro_idx[base + 2] = n;
        if (vo.w != 0.f) ro_idx[base + 3] = n;
    }
}

// ---------------------------------------------------------------------------
// Kernel 2: edge-weighted scatter-add.
// mi[b, ri, :] += e_w * X[b, ro, :];  mo[b, ro, :] += e_w * X[b, ri, :]
// 64 lanes per edge (one per feature d). Coalesced X reads and atomic targets.
// ---------------------------------------------------------------------------
__global__ __launch_bounds__(256) void scatter_kernel(
    const float* __restrict__ X, const float* __restrict__ ew,
    const int* __restrict__ ri_idx, const int* __restrict__ ro_idx,
    float* __restrict__ mi, float* __restrict__ mo)
{
    int t = blockIdx.x * blockDim.x + threadIdx.x;
    int edge = t >> 6;                 // global edge id in [0, B*E)
    int lane = t & 63;
    if (edge >= BB * EE) return;
    int b = edge >> 14;                // E = 2^14
    float w = ew[edge];                // e[] is [B,E] flat == edge
    int ri = ri_idx[edge];
    int ro = ro_idx[edge];
    const float* xb = X + (size_t)b * NN * DD;
    float xro = xb[ro * DD + lane];
    float xri = xb[ri * DD + lane];
    float* mib = mi + (size_t)b * NN * DD;
    float* mob = mo + (size_t)b * NN * DD;
    atomicAdd(&mib[ri * DD + lane], w * xro);
    atomicAdd(&mob[ro * DD + lane], w * xri);
}

// ---------------------------------------------------------------------------
// Kernel 3: per-node MLP. One node per thread.
// h = tanh([mi|mo|x] @ W1 + b1); out = tanh(h @ W2 + b2).
// W1/W2/b1/b2 accesses are thread-uniform -> compiler emits scalar s_loads
// (constant cache); per-node features via float4 vector loads (L2-resident,
// mi/mo were just written).
// ---------------------------------------------------------------------------
__global__ __launch_bounds__(64) void mlp_kernel(
    const float* __restrict__ X, const float* __restrict__ mi,
    const float* __restrict__ mo,
    const float* __restrict__ W1, const float* __restrict__ b1,
    const float* __restrict__ W2, const float* __restrict__ b2,
    float* __restrict__ out)
{
    int node = blockIdx.x * blockDim.x + threadIdx.x;
    if (node >= BB * NN) return;

    float acc[OO];
    #pragma unroll
    for (int j = 0; j < OO; ++j) acc[j] = b1[j];

    const float* srcs[3];
    srcs[0] = mi + (size_t)node * DD;
    srcs[1] = mo + (size_t)node * DD;
    srcs[2] = X  + (size_t)node * DD;

    for (int part = 0; part < 3; ++part) {
        const float* src = srcs[part];
        for (int kc = 0; kc < DD; kc += 4) {
            float4 hv = *(const float4*)(src + kc);
            const float* wrow = W1 + ((size_t)part * DD + kc) * OO;
            #pragma unroll
            for (int j = 0; j < OO; ++j) {
                acc[j] += hv.x * wrow[j]
                        + hv.y * wrow[OO + j]
                        + hv.z * wrow[2 * OO + j]
                        + hv.w * wrow[3 * OO + j];
            }
        }
    }

    // activation layer 1 (in-place: acc now holds h1)
    #pragma unroll
    for (int j = 0; j < OO; ++j) acc[j] = tanhf(acc[j]);

    float acc2[OO];
    #pragma unroll
    for (int j = 0; j < OO; ++j) acc2[j] = b2[j];

    for (int k = 0; k < OO; ++k) {
        const float* wrow = W2 + (size_t)k * OO;
        float hk = acc[k];
        #pragma unroll
        for (int j = 0; j < OO; ++j) acc2[j] += hk * wrow[j];
    }

    float* o = out + (size_t)node * OO;
    #pragma unroll
    for (int j = 0; j < OO; ++j) o[j] = tanhf(acc2[j]);
}

// ---------------------------------------------------------------------------
extern "C" void kernel_launch(void* const* d_in, const int* in_sizes, int n_in,
                              void* d_out, int out_size, void* d_ws, size_t ws_size,
                              hipStream_t stream)
{
    const float* X  = (const float*)d_in[0];   // [B,N,D]
    const float* ew = (const float*)d_in[1];   // [B,E]
    const float* Ri = (const float*)d_in[2];   // [B,N,E]
    const float* Ro = (const float*)d_in[3];   // [B,N,E]
    const float* W1 = (const float*)d_in[4];   // [3D,OUT]
    const float* b1 = (const float*)d_in[5];   // [OUT]
    const float* W2 = (const float*)d_in[6];   // [OUT,OUT]
    const float* b2 = (const float*)d_in[7];   // [OUT]
    float* out = (float*)d_out;                // [B,N,OUT]

    // workspace layout (ws re-poisoned each call -> re-init everything used)
    float* mi = (float*)d_ws;                            // 2 MB
    float* mo = mi + (size_t)BB * NN * DD;               // 2 MB
    int* ri_idx = (int*)(mo + (size_t)BB * NN * DD);     // 128 KB
    int* ro_idx = ri_idx + BB * EE;                      // 128 KB

    // zero the scatter accumulators (mi & mo are contiguous)
    hipMemsetAsync(mi, 0, (size_t)2 * BB * NN * DD * sizeof(float), stream);

    extract_idx_kernel<<<4096, 256, 0, stream>>>(Ri, Ro, ri_idx, ro_idx);

    scatter_kernel<<<(BB * EE * 64) / 256, 256, 0, stream>>>(
        X, ew, ri_idx, ro_idx, mi, mo);

    mlp_kernel<<<(BB * NN) / 64, 64, 0, stream>>>(
        X, mi, mo, W1, b1, W2, b2, out);
}

// Round 3
// 1007.090 us; speedup vs baseline: 1.1134x; 1.1134x over previous
//
#include <hip/hip_runtime.h>
#include <hip/hip_bf16.h>
#include <math.h>

// Problem constants (from reference): B=2, N=4096, E=16384, D=64, OUT=64
#define BB 2
#define NN 4096      // 2^12
#define EE 16384     // 2^14
#define DD 64
#define OO 64
// flat element index in [B,N,E]: fe = b*(N*E) + n*E + e ; N*E = 2^26, E = 2^14

// clang native vector type — required by __builtin_nontemporal_load
// (HIP's uint4 is a class template and is rejected by the builtin).
typedef unsigned int v4u __attribute__((ext_vector_type(4)));

// ---------------------------------------------------------------------------
// Kernel 1: recover ri_idx/ro_idx from the one-hot incidence matrices.
// Each [b,:,e] column has exactly one nonzero (1.0f) at row n -> unique writer
// per (b,e), plain stores. Must scan all 1.073 GB: this is the HBM floor of
// the whole problem. Unroll x2 (4x16B loads in flight), integer nonzero test,
// nontemporal loads (pure streaming, zero reuse).
// ---------------------------------------------------------------------------
__global__ __launch_bounds__(256) void extract_idx_kernel(
    const v4u* __restrict__ Ri, const v4u* __restrict__ Ro,
    int* __restrict__ ri_idx, int* __restrict__ ro_idx)
{
    const unsigned total8 = (unsigned)BB * NN * (EE / 8);   // 16,777,216 pairs of v4u
    unsigned stride = gridDim.x * blockDim.x;
    for (unsigned i = blockIdx.x * blockDim.x + threadIdx.x; i < total8; i += stride) {
        unsigned i4 = i * 2u;
        v4u a0 = __builtin_nontemporal_load(&Ri[i4]);
        v4u a1 = __builtin_nontemporal_load(&Ri[i4 + 1]);
        v4u c0 = __builtin_nontemporal_load(&Ro[i4]);
        v4u c1 = __builtin_nontemporal_load(&Ro[i4 + 1]);
        unsigned fe = i * 8u;                  // flat element index in [B,N,E]
        int e = (int)(fe & (EE - 1));          // 8 consecutive e's, same n,b
        int n = (int)((fe >> 14) & (NN - 1));
        int b = (int)(fe >> 26);
        int base = b * EE + e;
        if (a0.x) ri_idx[base + 0] = n;
        if (a0.y) ri_idx[base + 1] = n;
        if (a0.z) ri_idx[base + 2] = n;
        if (a0.w) ri_idx[base + 3] = n;
        if (a1.x) ri_idx[base + 4] = n;
        if (a1.y) ri_idx[base + 5] = n;
        if (a1.z) ri_idx[base + 6] = n;
        if (a1.w) ri_idx[base + 7] = n;
        if (c0.x) ro_idx[base + 0] = n;
        if (c0.y) ro_idx[base + 1] = n;
        if (c0.z) ro_idx[base + 2] = n;
        if (c0.w) ro_idx[base + 3] = n;
        if (c1.x) ro_idx[base + 4] = n;
        if (c1.y) ro_idx[base + 5] = n;
        if (c1.z) ro_idx[base + 6] = n;
        if (c1.w) ro_idx[base + 7] = n;
    }
}

// ---------------------------------------------------------------------------
// Kernel 2: edge-weighted scatter-add.
// mi[b,ri,:] += w * X[b,ro,:];  mo[b,ro,:] += w * X[b,ri,:]
// 64 lanes per edge (one per feature). Coalesced gathers and atomic targets.
// ---------------------------------------------------------------------------
__global__ __launch_bounds__(256) void scatter_kernel(
    const float* __restrict__ X, const float* __restrict__ ew,
    const int* __restrict__ ri_idx, const int* __restrict__ ro_idx,
    float* __restrict__ mi, float* __restrict__ mo)
{
    int t = blockIdx.x * blockDim.x + threadIdx.x;
    int edge = t >> 6;                 // global edge id in [0, B*E)
    int lane = t & 63;
    if (edge >= BB * EE) return;
    int b = edge >> 14;                // E = 2^14
    float w = ew[edge];
    int ri = ri_idx[edge];
    int ro = ro_idx[edge];
    const float* xb = X + (size_t)b * NN * DD;
    float xro = xb[ro * DD + lane];
    float xri = xb[ri * DD + lane];
    float* mib = mi + (size_t)b * NN * DD;
    float* mob = mo + (size_t)b * NN * DD;
    atomicAdd(&mib[ri * DD + lane], w * xro);
    atomicAdd(&mob[ro * DD + lane], w * xri);
}

// ---------------------------------------------------------------------------
// Kernel 3: per-node MLP, one WAVE per node, lane j = output channel.
// acc_j = b1[j] + sum_k feat[k]*W1[k][j]; h=tanh; out_j = tanh(b2[j]+sum h W2).
// Features broadcast via __shfl; W rows are coalesced 256B loads (64KB working
// set, L1/L2-hot). 8192 waves -> full occupancy, ~1 VGPR accumulator.
// ---------------------------------------------------------------------------
__global__ __launch_bounds__(256) void mlp_kernel(
    const float* __restrict__ X, const float* __restrict__ mi,
    const float* __restrict__ mo,
    const float* __restrict__ W1, const float* __restrict__ b1,
    const float* __restrict__ W2, const float* __restrict__ b2,
    float* __restrict__ out)
{
    int wid = (blockIdx.x * blockDim.x + threadIdx.x) >> 6;   // node id
    int lane = threadIdx.x & 63;
    if (wid >= BB * NN) return;

    float acc = b1[lane];
    const float* srcs[3];
    srcs[0] = mi + (size_t)wid * DD;
    srcs[1] = mo + (size_t)wid * DD;
    srcs[2] = X  + (size_t)wid * DD;

    for (int part = 0; part < 3; ++part) {
        float fv = srcs[part][lane];          // lane k holds feat[k]
        const float* wbase = W1 + (size_t)part * DD * OO;
        #pragma unroll
        for (int k = 0; k < DD; ++k) {
            float fk = __shfl(fv, k, 64);
            acc += fk * wbase[k * OO + lane]; // coalesced row, L1-hot
        }
    }
    float h = tanhf(acc);

    float acc2 = b2[lane];
    #pragma unroll
    for (int k = 0; k < OO; ++k) {
        float hk = __shfl(h, k, 64);
        acc2 += hk * W2[k * OO + lane];
    }
    out[(size_t)wid * OO + lane] = tanhf(acc2);
}

// ---------------------------------------------------------------------------
extern "C" void kernel_launch(void* const* d_in, const int* in_sizes, int n_in,
                              void* d_out, int out_size, void* d_ws, size_t ws_size,
                              hipStream_t stream)
{
    const float* X  = (const float*)d_in[0];   // [B,N,D]
    const float* ew = (const float*)d_in[1];   // [B,E]
    const float* Ri = (const float*)d_in[2];   // [B,N,E]
    const float* Ro = (const float*)d_in[3];   // [B,N,E]
    const float* W1 = (const float*)d_in[4];   // [3D,OUT]
    const float* b1 = (const float*)d_in[5];   // [OUT]
    const float* W2 = (const float*)d_in[6];   // [OUT,OUT]
    const float* b2 = (const float*)d_in[7];   // [OUT]
    float* out = (float*)d_out;                // [B,N,OUT]

    // workspace layout (ws re-poisoned to 0xAA each call -> re-init all of it)
    float* mi = (float*)d_ws;                            // 2 MB
    float* mo = mi + (size_t)BB * NN * DD;               // 2 MB
    int* ri_idx = (int*)(mo + (size_t)BB * NN * DD);     // 128 KB
    int* ro_idx = ri_idx + BB * EE;                      // 128 KB

    // zero the scatter accumulators (mi & mo are contiguous)
    (void)hipMemsetAsync(mi, 0, (size_t)2 * BB * NN * DD * sizeof(float), stream);

    extract_idx_kernel<<<4096, 256, 0, stream>>>(
        (const v4u*)Ri, (const v4u*)Ro, ri_idx, ro_idx);

    scatter_kernel<<<(BB * EE * 64) / 256, 256, 0, stream>>>(
        X, ew, ri_idx, ro_idx, mi, mo);

    mlp_kernel<<<(BB * NN * 64) / 256, 256, 0, stream>>>(
        X, mi, mo, W1, b1, W2, b2, out);
}